// Round 1
// 1041.740 us; speedup vs baseline: 1.0220x; 1.0220x over previous
//
#include <hip/hip_runtime.h>

typedef __bf16 bf16;
typedef bf16 bf16x8 __attribute__((ext_vector_type(8)));
typedef bf16 bf16x4 __attribute__((ext_vector_type(4)));
typedef float f32x4 __attribute__((ext_vector_type(4)));

#define N_NODES 65536
#define E_EDGES 262144
#define EDIM    300
#define HDIM    256
#define KCAT    576   // 320 (x zero-padded 300->320) + 256 (h_tilde)
#define NCAT    1024  // 768 (z_i|z_o|z_u) + 256 (x@W_f)

__device__ __forceinline__ float sigmoidf_(float x) {
    return 1.0f / (1.0f + __expf(-x));
}
// fast tanh via exp; exact at +-inf saturation
__device__ __forceinline__ float tanhf_(float x) {
    float e = __expf(2.0f * x);
    return 1.0f - 2.0f / (e + 1.0f);
}

// async global->LDS, 16B per lane; LDS dest = base + lane*16 (wave-uniform base)
__device__ __forceinline__ void gload_lds16(const void* g, void* l) {
    __builtin_amdgcn_global_load_lds(
        (const __attribute__((address_space(1))) void*)g,
        (__attribute__((address_space(3))) void*)l, 16, 0, 0);
}

// ---------------------------------------------------------------------------
// Pack weights: B^T (bf16) for both GEMMs + fused bias vector.
// ---------------------------------------------------------------------------
__global__ __launch_bounds__(256) void pack_weights_kernel(
    const float* __restrict__ Wc, const float* __restrict__ Wf,
    const float* __restrict__ Uf, const float* __restrict__ bc,
    bf16* __restrict__ BTcat, bf16* __restrict__ BTu, float* __restrict__ biascat) {
    const int SZ1 = NCAT * KCAT;   // 589824
    const int SZ2 = HDIM * HDIM;   // 65536
    int idx = blockIdx.x * 256 + threadIdx.x;
    if (idx < SZ1) {
        int n = idx / KCAT, k = idx % KCAT;
        float v = 0.f;
        if (n < 768) {
            if (k < EDIM) v = Wc[k * 768 + n];
            else if (k >= 320) v = Wc[(k - 20) * 768 + n];
        } else {
            if (k < EDIM) v = Wf[k * HDIM + (n - 768)];
        }
        BTcat[idx] = (bf16)v;
    } else if (idx < SZ1 + SZ2) {
        int i = idx - SZ1;
        int n = i / HDIM, k = i % HDIM;
        BTu[i] = (bf16)Uf[k * HDIM + n];
    } else if (idx < SZ1 + SZ2 + NCAT) {
        int n = idx - SZ1 - SZ2;
        biascat[n] = (n < 768) ? bc[n] : 0.f;
    }
}

// x (f32 [N,300]) -> Acat[:, 0:320] bf16 (zero pad 300..319), vectorized:
// each thread covers 8 consecutive cols of the 320 (40 groups/row).
__global__ __launch_bounds__(256) void convert_x_kernel(
    const float* __restrict__ x, bf16* __restrict__ Acat) {
    int i = blockIdx.x * 256 + threadIdx.x;   // over N*40
    int row = i / 40;
    int c0 = (i - row * 40) * 8;
    bf16x8 o;
    if (c0 + 8 <= EDIM) {
        float4 a = *(const float4*)(x + (size_t)row * EDIM + c0);
        float4 b = *(const float4*)(x + (size_t)row * EDIM + c0 + 4);
        o[0] = (bf16)a.x; o[1] = (bf16)a.y; o[2] = (bf16)a.z; o[3] = (bf16)a.w;
        o[4] = (bf16)b.x; o[5] = (bf16)b.y; o[6] = (bf16)b.z; o[7] = (bf16)b.w;
    } else {
#pragma unroll
        for (int u = 0; u < 8; ++u) {
            int c = c0 + u;
            o[u] = (bf16)((c < EDIM) ? x[(size_t)row * EDIM + c] : 0.f);
        }
    }
    *(bf16x8*)(Acat + (size_t)row * KCAT + c0) = o;
}

// start[j] = lower_bound(seg, j); edges of node j = [start[j], start[j+1])
__global__ __launch_bounds__(256) void seg_start_kernel(
    const int* __restrict__ seg, int* __restrict__ start) {
    int j = blockIdx.x * 256 + threadIdx.x;
    if (j > N_NODES) return;
    int lo = 0, hi = E_EDGES;
    while (lo < hi) {
        int mid = (lo + hi) >> 1;
        if (seg[mid] < j) lo = mid + 1; else hi = mid;
    }
    start[j] = lo;
}

// FUSED: prev_h f32 -> bf16 copy AND h_tilde segment-sum, single pass over ph.
// Block per node; thread t owns column t. Edges are disjoint across nodes.
__global__ __launch_bounds__(256) void phconv_htilde_kernel(
    const float* __restrict__ ph, const int* __restrict__ start,
    bf16* __restrict__ phb, bf16* __restrict__ Acat) {
    int j = blockIdx.x;
    int t = threadIdx.x;
    int s = start[j], e = start[j + 1];
    float acc = 0.f;
    for (int k = s; k < e; ++k) {
        float v = ph[(size_t)k * HDIM + t];
        phb[(size_t)k * HDIM + t] = (bf16)v;
        acc += v;
    }
    Acat[(size_t)j * KCAT + 320 + t] = (bf16)acc;
}

// ---------------------------------------------------------------------------
// GEMM: C[M,Nc] = A[M,K](bf16,rm) * BT[Nc,K](bf16,rm)^T + bias
// 128x128 tile, 4 waves, 4x4 of 16x16x32 MFMA per wave.
// Staging via global_load_lds width=16 into LINEAR [128][32] LDS:
//  - no ds_write path, no staging VGPRs
//  - frag reads are 1024 contiguous bytes per wave -> bank-conflict-free
// ---------------------------------------------------------------------------
template <typename OutT>
__global__ __launch_bounds__(256) void gemm_tn(
    const bf16* __restrict__ A, const bf16* __restrict__ BT,
    OutT* __restrict__ C, const float* __restrict__ bias, int K, int ldc) {
    __shared__ bf16 As[128][32];
    __shared__ bf16 Bs[128][32];

    const int tid = threadIdx.x;
    const int m0 = blockIdx.x * 128;
    const int n0 = blockIdx.y * 128;
    const int lane = tid & 63;
    const int w = tid >> 6;
    const int wm = (w >> 1) * 64;
    const int wn = (w & 1) * 64;
    const int l15 = lane & 15;
    const int kf = (lane >> 4) * 8;

    // staging: wave w covers tile rows [32w, 32w+32); each gl_lds moves 16 rows
    const int srow = w * 32 + (lane >> 2);
    const int scol = (lane & 3) * 8;
    const bf16* gA = A + (size_t)(m0 + srow) * K + scol;
    const bf16* gB = BT + (size_t)(n0 + srow) * K + scol;
    const size_t rs16 = (size_t)16 * K;
    bf16* lA0 = &As[w * 32][0];
    bf16* lA1 = &As[w * 32 + 16][0];
    bf16* lB0 = &Bs[w * 32][0];
    bf16* lB1 = &Bs[w * 32 + 16][0];

    f32x4 acc[4][4] = {};

    for (int k0 = 0; k0 < K; k0 += 32) {
        gload_lds16(gA + k0, lA0);
        gload_lds16(gA + k0 + rs16, lA1);
        gload_lds16(gB + k0, lB0);
        gload_lds16(gB + k0 + rs16, lB1);
        __syncthreads();   // compiler drains vmcnt before barrier

        bf16x8 af[4], bg[4];
#pragma unroll
        for (int i = 0; i < 4; ++i) af[i] = *(const bf16x8*)&As[wm + i * 16 + l15][kf];
#pragma unroll
        for (int j = 0; j < 4; ++j) bg[j] = *(const bf16x8*)&Bs[wn + j * 16 + l15][kf];
#pragma unroll
        for (int i = 0; i < 4; ++i)
#pragma unroll
            for (int j = 0; j < 4; ++j)
                acc[i][j] = __builtin_amdgcn_mfma_f32_16x16x32_bf16(af[i], bg[j], acc[i][j], 0, 0, 0);
        __syncthreads();   // protect LDS before next stage overwrites
    }

    const int r0 = (lane >> 4) * 4;
#pragma unroll
    for (int i = 0; i < 4; ++i) {
#pragma unroll
        for (int j = 0; j < 4; ++j) {
            const int col = n0 + wn + j * 16 + l15;
            const float bv = bias ? bias[col] : 0.f;
            const int row = m0 + wm + i * 16 + r0;
#pragma unroll
            for (int r = 0; r < 4; ++r) {
                C[(size_t)(row + r) * ldc + col] = (OutT)(acc[i][j][r] + bv);
            }
        }
    }
}

// ---------------------------------------------------------------------------
// Fused epilogue, one block per node:
//   f_jk = sigmoid(xWf[j] + hU[e] + b_f); fc = sum f*prev_c over child edges
//   c = sig(z_i)*tanh(z_u) + fc;  h = sig(z_o)*tanh(c)
// ---------------------------------------------------------------------------
__global__ __launch_bounds__(256) void final_kernel(
    const float* __restrict__ C1, const bf16* __restrict__ hU,
    const float* __restrict__ prev_c, const float* __restrict__ b_f,
    const int* __restrict__ start, float* __restrict__ out) {
    int j = blockIdx.x;
    int t = threadIdx.x;
    const float* row = C1 + (size_t)j * NCAT;
    float zi  = row[t];
    float zo  = row[HDIM + t];
    float zu  = row[2 * HDIM + t];
    float xwf = row[3 * HDIM + t];
    float bfv = b_f[t];

    int s = start[j], e = start[j + 1];
    float acc = 0.f;
    for (int k = s; k < e; ++k) {
        float u = (float)hU[(size_t)k * HDIM + t];
        float f = sigmoidf_(xwf + u + bfv);
        acc += f * prev_c[(size_t)k * HDIM + t];
    }
    float c = sigmoidf_(zi) * tanhf_(zu) + acc;
    float h = sigmoidf_(zo) * tanhf_(c);
    out[(size_t)j * HDIM + t] = c;
    out[(size_t)N_NODES * HDIM + (size_t)j * HDIM + t] = h;
}

extern "C" void kernel_launch(void* const* d_in, const int* in_sizes, int n_in,
                              void* d_out, int out_size, void* d_ws, size_t ws_size,
                              hipStream_t stream) {
    const float* x   = (const float*)d_in[0];
    const float* pc  = (const float*)d_in[1];
    const float* ph  = (const float*)d_in[2];
    const float* Wc  = (const float*)d_in[3];
    const float* bc  = (const float*)d_in[4];
    const float* Wf  = (const float*)d_in[5];
    const float* Uf  = (const float*)d_in[6];
    const float* bf_ = (const float*)d_in[7];
    const int*   seg = (const int*)d_in[8];
    float* out = (float*)d_out;

    char* ws = (char*)d_ws;
    size_t off = 0;
    auto alloc = [&](size_t bytes) -> void* {
        void* p = ws + off;
        off += (bytes + 255) & ~(size_t)255;
        return p;
    };
    bf16*  Acat    = (bf16*)alloc((size_t)N_NODES * KCAT * 2);   // 75.5 MB
    bf16*  BTcat   = (bf16*)alloc((size_t)NCAT * KCAT * 2);      // 1.2 MB
    bf16*  BTu     = (bf16*)alloc((size_t)HDIM * HDIM * 2);      // 128 KB
    float* biascat = (float*)alloc((size_t)NCAT * 4);            // 4 KB
    bf16*  phb     = (bf16*)alloc((size_t)E_EDGES * HDIM * 2);   // 134 MB
    float* C1      = (float*)alloc((size_t)N_NODES * NCAT * 4);  // 268 MB
    bf16*  hU      = (bf16*)alloc((size_t)E_EDGES * HDIM * 2);   // 134 MB
    int*   start   = (int*)alloc((size_t)(N_NODES + 1) * 4);     // 256 KB

    pack_weights_kernel<<<2564, 256, 0, stream>>>(Wc, Wf, Uf, bc, BTcat, BTu, biascat);
    convert_x_kernel<<<(N_NODES * 40) / 256, 256, 0, stream>>>(x, Acat);
    seg_start_kernel<<<257, 256, 0, stream>>>(seg, start);
    phconv_htilde_kernel<<<N_NODES, 256, 0, stream>>>(ph, start, phb, Acat);
    gemm_tn<float><<<dim3(N_NODES / 128, NCAT / 128), 256, 0, stream>>>(
        Acat, BTcat, C1, biascat, KCAT, NCAT);
    gemm_tn<bf16><<<dim3(E_EDGES / 128, HDIM / 128), 256, 0, stream>>>(
        phb, BTu, hU, nullptr, HDIM, HDIM);
    final_kernel<<<N_NODES, 256, 0, stream>>>(C1, hU, pc, bf_, start, out);
}

// Round 2
// 945.878 us; speedup vs baseline: 1.1255x; 1.1013x over previous
//
#include <hip/hip_runtime.h>

typedef __bf16 bf16;
typedef bf16 bf16x8 __attribute__((ext_vector_type(8)));
typedef bf16 bf16x4 __attribute__((ext_vector_type(4)));
typedef float f32x4 __attribute__((ext_vector_type(4)));

#define N_NODES 65536
#define E_EDGES 262144
#define EDIM    300
#define HDIM    256
#define KCAT    576   // 320 (x zero-padded 300->320) + 256 (h_tilde)
#define NCAT    1024  // 768 (z_i|z_o|z_u) + 256 (x@W_f)

__device__ __forceinline__ float sigmoidf_(float x) {
    return 1.0f / (1.0f + __expf(-x));
}
// fast tanh via exp; exact at +-inf saturation
__device__ __forceinline__ float tanhf_(float x) {
    float e = __expf(2.0f * x);
    return 1.0f - 2.0f / (e + 1.0f);
}

// async global->LDS, 16B per lane; LDS dest = base + lane*16 (wave-uniform base)
__device__ __forceinline__ void gload_lds16(const void* g, void* l) {
    __builtin_amdgcn_global_load_lds(
        (const __attribute__((address_space(1))) void*)g,
        (__attribute__((address_space(3))) void*)l, 16, 0, 0);
}

// ---------------------------------------------------------------------------
// Pack weights: B^T (bf16) for both GEMMs + fused bias vector.
// ---------------------------------------------------------------------------
__global__ __launch_bounds__(256) void pack_weights_kernel(
    const float* __restrict__ Wc, const float* __restrict__ Wf,
    const float* __restrict__ Uf, const float* __restrict__ bc,
    bf16* __restrict__ BTcat, bf16* __restrict__ BTu, float* __restrict__ biascat) {
    const int SZ1 = NCAT * KCAT;   // 589824
    const int SZ2 = HDIM * HDIM;   // 65536
    int idx = blockIdx.x * 256 + threadIdx.x;
    if (idx < SZ1) {
        int n = idx / KCAT, k = idx % KCAT;
        float v = 0.f;
        if (n < 768) {
            if (k < EDIM) v = Wc[k * 768 + n];
            else if (k >= 320) v = Wc[(k - 20) * 768 + n];
        } else {
            if (k < EDIM) v = Wf[k * HDIM + (n - 768)];
        }
        BTcat[idx] = (bf16)v;
    } else if (idx < SZ1 + SZ2) {
        int i = idx - SZ1;
        int n = i / HDIM, k = i % HDIM;
        BTu[i] = (bf16)Uf[k * HDIM + n];
    } else if (idx < SZ1 + SZ2 + NCAT) {
        int n = idx - SZ1 - SZ2;
        biascat[n] = (n < 768) ? bc[n] : 0.f;
    }
}

// x (f32 [N,300]) -> Acat[:, 0:320] bf16 (zero pad 300..319), vectorized:
// each thread covers 8 consecutive cols of the 320 (40 groups/row).
__global__ __launch_bounds__(256) void convert_x_kernel(
    const float* __restrict__ x, bf16* __restrict__ Acat) {
    int i = blockIdx.x * 256 + threadIdx.x;   // over N*40
    int row = i / 40;
    int c0 = (i - row * 40) * 8;
    bf16x8 o;
    if (c0 + 8 <= EDIM) {
        float4 a = *(const float4*)(x + (size_t)row * EDIM + c0);
        float4 b = *(const float4*)(x + (size_t)row * EDIM + c0 + 4);
        o[0] = (bf16)a.x; o[1] = (bf16)a.y; o[2] = (bf16)a.z; o[3] = (bf16)a.w;
        o[4] = (bf16)b.x; o[5] = (bf16)b.y; o[6] = (bf16)b.z; o[7] = (bf16)b.w;
    } else {
#pragma unroll
        for (int u = 0; u < 8; ++u) {
            int c = c0 + u;
            o[u] = (bf16)((c < EDIM) ? x[(size_t)row * EDIM + c] : 0.f);
        }
    }
    *(bf16x8*)(Acat + (size_t)row * KCAT + c0) = o;
}

// start[j] = lower_bound(seg, j); edges of node j = [start[j], start[j+1])
__global__ __launch_bounds__(256) void seg_start_kernel(
    const int* __restrict__ seg, int* __restrict__ start) {
    int j = blockIdx.x * 256 + threadIdx.x;
    if (j > N_NODES) return;
    int lo = 0, hi = E_EDGES;
    while (lo < hi) {
        int mid = (lo + hi) >> 1;
        if (seg[mid] < j) lo = mid + 1; else hi = mid;
    }
    start[j] = lo;
}

// FUSED: prev_h f32 -> bf16 copy AND h_tilde segment-sum, single pass over ph.
// Wave per node (4 nodes / 256-thr block); lane owns 4 consecutive columns.
// float4 reads (16B/lane), bf16x4 writes (8B/lane) -> fully coalesced.
__global__ __launch_bounds__(256) void phconv_htilde_kernel(
    const float* __restrict__ ph, const int* __restrict__ start,
    bf16* __restrict__ phb, bf16* __restrict__ Acat) {
    const int j = blockIdx.x * 4 + (threadIdx.x >> 6);
    const int c0 = (threadIdx.x & 63) * 4;
    const int s = start[j], e = start[j + 1];
    float ax = 0.f, ay = 0.f, az = 0.f, aw = 0.f;
    for (int k = s; k < e; ++k) {
        float4 v = *(const float4*)(ph + (size_t)k * HDIM + c0);
        bf16x4 o;
        o[0] = (bf16)v.x; o[1] = (bf16)v.y; o[2] = (bf16)v.z; o[3] = (bf16)v.w;
        *(bf16x4*)(phb + (size_t)k * HDIM + c0) = o;
        ax += v.x; ay += v.y; az += v.z; aw += v.w;
    }
    bf16x4 a;
    a[0] = (bf16)ax; a[1] = (bf16)ay; a[2] = (bf16)az; a[3] = (bf16)aw;
    *(bf16x4*)(Acat + (size_t)j * KCAT + 320 + c0) = a;
}

// ---------------------------------------------------------------------------
// GEMM: C[M,Nc] = A[M,K](bf16,rm) * BT[Nc,K](bf16,rm)^T + bias
// 128x128 tile, 4 waves, 4x4 of 16x16x32 MFMA per wave.
// Staging via global_load_lds width=16 into LINEAR [128][32] LDS.
// ---------------------------------------------------------------------------
template <typename OutT>
__global__ __launch_bounds__(256) void gemm_tn(
    const bf16* __restrict__ A, const bf16* __restrict__ BT,
    OutT* __restrict__ C, const float* __restrict__ bias, int K, int ldc) {
    __shared__ bf16 As[128][32];
    __shared__ bf16 Bs[128][32];

    const int tid = threadIdx.x;
    const int m0 = blockIdx.x * 128;
    const int n0 = blockIdx.y * 128;
    const int lane = tid & 63;
    const int w = tid >> 6;
    const int wm = (w >> 1) * 64;
    const int wn = (w & 1) * 64;
    const int l15 = lane & 15;
    const int kf = (lane >> 4) * 8;

    // staging: wave w covers tile rows [32w, 32w+32); each gl_lds moves 16 rows
    const int srow = w * 32 + (lane >> 2);
    const int scol = (lane & 3) * 8;
    const bf16* gA = A + (size_t)(m0 + srow) * K + scol;
    const bf16* gB = BT + (size_t)(n0 + srow) * K + scol;
    const size_t rs16 = (size_t)16 * K;
    bf16* lA0 = &As[w * 32][0];
    bf16* lA1 = &As[w * 32 + 16][0];
    bf16* lB0 = &Bs[w * 32][0];
    bf16* lB1 = &Bs[w * 32 + 16][0];

    f32x4 acc[4][4] = {};

    for (int k0 = 0; k0 < K; k0 += 32) {
        gload_lds16(gA + k0, lA0);
        gload_lds16(gA + k0 + rs16, lA1);
        gload_lds16(gB + k0, lB0);
        gload_lds16(gB + k0 + rs16, lB1);
        __syncthreads();   // compiler drains vmcnt before barrier

        bf16x8 af[4], bg[4];
#pragma unroll
        for (int i = 0; i < 4; ++i) af[i] = *(const bf16x8*)&As[wm + i * 16 + l15][kf];
#pragma unroll
        for (int j = 0; j < 4; ++j) bg[j] = *(const bf16x8*)&Bs[wn + j * 16 + l15][kf];
#pragma unroll
        for (int i = 0; i < 4; ++i)
#pragma unroll
            for (int j = 0; j < 4; ++j)
                acc[i][j] = __builtin_amdgcn_mfma_f32_16x16x32_bf16(af[i], bg[j], acc[i][j], 0, 0, 0);
        __syncthreads();   // protect LDS before next stage overwrites
    }

    const int r0 = (lane >> 4) * 4;
#pragma unroll
    for (int i = 0; i < 4; ++i) {
#pragma unroll
        for (int j = 0; j < 4; ++j) {
            const int col = n0 + wn + j * 16 + l15;
            const float bv = bias ? bias[col] : 0.f;
            const int row = m0 + wm + i * 16 + r0;
#pragma unroll
            for (int r = 0; r < 4; ++r) {
                C[(size_t)(row + r) * ldc + col] = (OutT)(acc[i][j][r] + bv);
            }
        }
    }
}

// ---------------------------------------------------------------------------
// Fused epilogue. Wave per node (4 nodes / 256-thr block); lane owns 4 cols.
//   f_jk = sigmoid(xWf[j] + hU[e] + b_f); fc = sum f*prev_c over child edges
//   c = sig(z_i)*tanh(z_u) + fc;  h = sig(z_o)*tanh(c)
// C1 is bf16 (z's already bias-added by GEMM).
// ---------------------------------------------------------------------------
__global__ __launch_bounds__(256) void final_kernel(
    const bf16* __restrict__ C1, const bf16* __restrict__ hU,
    const float* __restrict__ prev_c, const float* __restrict__ b_f,
    const int* __restrict__ start, float* __restrict__ out) {
    const int j = blockIdx.x * 4 + (threadIdx.x >> 6);
    const int c0 = (threadIdx.x & 63) * 4;
    const bf16* row = C1 + (size_t)j * NCAT;
    bf16x4 zi4 = *(const bf16x4*)(row + c0);
    bf16x4 zo4 = *(const bf16x4*)(row + HDIM + c0);
    bf16x4 zu4 = *(const bf16x4*)(row + 2 * HDIM + c0);
    bf16x4 xw4 = *(const bf16x4*)(row + 3 * HDIM + c0);
    float4 bf4 = *(const float4*)(b_f + c0);
    float xwf[4];
    xwf[0] = (float)xw4[0] + bf4.x;
    xwf[1] = (float)xw4[1] + bf4.y;
    xwf[2] = (float)xw4[2] + bf4.z;
    xwf[3] = (float)xw4[3] + bf4.w;

    const int s = start[j], e = start[j + 1];
    float acc[4] = {0.f, 0.f, 0.f, 0.f};
    for (int k = s; k < e; ++k) {
        bf16x4 u4 = *(const bf16x4*)(hU + (size_t)k * HDIM + c0);
        float4 pc4 = *(const float4*)(prev_c + (size_t)k * HDIM + c0);
        acc[0] += sigmoidf_(xwf[0] + (float)u4[0]) * pc4.x;
        acc[1] += sigmoidf_(xwf[1] + (float)u4[1]) * pc4.y;
        acc[2] += sigmoidf_(xwf[2] + (float)u4[2]) * pc4.z;
        acc[3] += sigmoidf_(xwf[3] + (float)u4[3]) * pc4.w;
    }
    float4 cv, hv;
    float c0v = sigmoidf_((float)zi4[0]) * tanhf_((float)zu4[0]) + acc[0];
    float c1v = sigmoidf_((float)zi4[1]) * tanhf_((float)zu4[1]) + acc[1];
    float c2v = sigmoidf_((float)zi4[2]) * tanhf_((float)zu4[2]) + acc[2];
    float c3v = sigmoidf_((float)zi4[3]) * tanhf_((float)zu4[3]) + acc[3];
    cv.x = c0v; cv.y = c1v; cv.z = c2v; cv.w = c3v;
    hv.x = sigmoidf_((float)zo4[0]) * tanhf_(c0v);
    hv.y = sigmoidf_((float)zo4[1]) * tanhf_(c1v);
    hv.z = sigmoidf_((float)zo4[2]) * tanhf_(c2v);
    hv.w = sigmoidf_((float)zo4[3]) * tanhf_(c3v);
    *(float4*)(out + (size_t)j * HDIM + c0) = cv;
    *(float4*)(out + (size_t)N_NODES * HDIM + (size_t)j * HDIM + c0) = hv;
}

extern "C" void kernel_launch(void* const* d_in, const int* in_sizes, int n_in,
                              void* d_out, int out_size, void* d_ws, size_t ws_size,
                              hipStream_t stream) {
    const float* x   = (const float*)d_in[0];
    const float* pc  = (const float*)d_in[1];
    const float* ph  = (const float*)d_in[2];
    const float* Wc  = (const float*)d_in[3];
    const float* bc  = (const float*)d_in[4];
    const float* Wf  = (const float*)d_in[5];
    const float* Uf  = (const float*)d_in[6];
    const float* bf_ = (const float*)d_in[7];
    const int*   seg = (const int*)d_in[8];
    float* out = (float*)d_out;

    char* ws = (char*)d_ws;
    size_t off = 0;
    auto alloc = [&](size_t bytes) -> void* {
        void* p = ws + off;
        off += (bytes + 255) & ~(size_t)255;
        return p;
    };
    bf16*  Acat    = (bf16*)alloc((size_t)N_NODES * KCAT * 2);   // 75.5 MB
    bf16*  BTcat   = (bf16*)alloc((size_t)NCAT * KCAT * 2);      // 1.2 MB
    bf16*  BTu     = (bf16*)alloc((size_t)HDIM * HDIM * 2);      // 128 KB
    float* biascat = (float*)alloc((size_t)NCAT * 4);            // 4 KB
    bf16*  phb     = (bf16*)alloc((size_t)E_EDGES * HDIM * 2);   // 134 MB
    bf16*  C1      = (bf16*)alloc((size_t)N_NODES * NCAT * 2);   // 134 MB (was f32)
    bf16*  hU      = (bf16*)alloc((size_t)E_EDGES * HDIM * 2);   // 134 MB
    int*   start   = (int*)alloc((size_t)(N_NODES + 1) * 4);     // 256 KB

    pack_weights_kernel<<<2564, 256, 0, stream>>>(Wc, Wf, Uf, bc, BTcat, BTu, biascat);
    convert_x_kernel<<<(N_NODES * 40) / 256, 256, 0, stream>>>(x, Acat);
    seg_start_kernel<<<257, 256, 0, stream>>>(seg, start);
    phconv_htilde_kernel<<<N_NODES / 4, 256, 0, stream>>>(ph, start, phb, Acat);
    gemm_tn<bf16><<<dim3(N_NODES / 128, NCAT / 128), 256, 0, stream>>>(
        Acat, BTcat, C1, biascat, KCAT, NCAT);
    gemm_tn<bf16><<<dim3(E_EDGES / 128, HDIM / 128), 256, 0, stream>>>(
        phb, BTu, hU, nullptr, HDIM, HDIM);
    final_kernel<<<N_NODES / 4, 256, 0, stream>>>(C1, hU, pc, bf_, start, out);
}